// Round 2
// baseline (159.739 us; speedup 1.0000x reference)
//
#include <hip/hip_runtime.h>
#include <math.h>

// Problem geometry (from reference): x [8, 64, 256, 256, 2] fp32
// slab = one (b, ch) contiguous run = 256*256*2 = 131072 floats = 32768 float4
#define NCH      64
#define NB       8
#define NSLAB    512                 // 8 * 64
#define SLAB4    32768               // float4 per slab
#define BPS      4                   // blocks per slab
#define CHUNK4   (SLAB4 / BPS)       // 8192 float4 per block
#define NTHREADS 256
#define ITERS    (CHUNK4 / NTHREADS) // 32
#define NSEG     16
#define NPART    (NSLAB * BPS)       // 2048 partial sums
#define PER_CH_ELEMS 1048576.0f      // 8*256*256*2 elements per channel

__device__ __constant__ int c_seg_id[NCH] = {
    0,1,2,3,
    4,4,4, 5,5,5, 6,6,6, 7,7,7,
    8,8,8,8,8, 9,9,9,9,9, 10,10,10,10,10, 11,11,11,11,11,
    12,12,12,12,12,12,12, 13,13,13,13,13,13,13,
    14,14,14,14,14,14,14, 15,15,15,15,15,15,15
};
__device__ __constant__ int c_seg_lo[NSEG]  = {0,1,2,3, 4,7,10,13, 16,21,26,31, 36,43,50,57};
__device__ __constant__ int c_seg_sz[NSEG]  = {1,1,1,1, 3,3,3,3,   5,5,5,5,     7,7,7,7};

// ---------------- pass 1: per-block partial sums of |x| (plain stores, no atomics) ----
__global__ __launch_bounds__(NTHREADS) void k_reduce_abs(
        const float4* __restrict__ x4, float* __restrict__ partial) {
    const long base = (long)blockIdx.x * CHUNK4 + threadIdx.x;

    float s = 0.0f;
    #pragma unroll
    for (int k = 0; k < ITERS; ++k) {
        float4 v = x4[base + (long)k * NTHREADS];
        s += fabsf(v.x) + fabsf(v.y) + fabsf(v.z) + fabsf(v.w);
    }
    // 64-lane wave reduction
    #pragma unroll
    for (int off = 32; off >= 1; off >>= 1) s += __shfl_down(s, off, 64);

    __shared__ float sm[NTHREADS / 64];
    const int lane = threadIdx.x & 63;
    const int wid  = threadIdx.x >> 6;
    if (lane == 0) sm[wid] = s;
    __syncthreads();
    if (threadIdx.x == 0)
        partial[blockIdx.x] = sm[0] + sm[1] + sm[2] + sm[3];   // overwrite, never accumulate
}

// ---------------- pass 2: reduce partials -> EMA -> per-channel scale ----------------
// partial index = (b*NCH + ch)*BPS + sub ; for channel ch: 8 b's x 4 subs = 32 values
__global__ __launch_bounds__(64) void k_stats(
        const float* __restrict__ partial, const float* __restrict__ sigma2,
        const int* __restrict__ update, float* __restrict__ chscale) {
    __shared__ float cm[NCH];
    __shared__ float sscale[NSEG];
    const int t = threadIdx.x;           // 64 threads, 1 wave: t = channel
    float s = 0.0f;
    for (int b = 0; b < NB; ++b) {
        const int base = (b * NCH + t) * BPS;
        s += partial[base] + partial[base + 1] + partial[base + 2] + partial[base + 3];
    }
    cm[t] = s * (1.0f / PER_CH_ELEMS);
    __syncthreads();
    if (t < NSEG) {
        const int lo = c_seg_lo[t];
        const int n  = c_seg_sz[t];
        float ssum = 0.0f;
        for (int c = lo; c < lo + n; ++c) ssum += cm[c];
        const float s2  = ssum / (float)n;
        const float old = sigma2[t];
        float snew;
        if (update[0] != 0) snew = (old == 0.0f) ? s2 : old * 0.9f + s2 * 0.1f;
        else                snew = old;
        sscale[t] = 1.0f / (sqrtf(snew) + 1e-5f);
    }
    __syncthreads();
    chscale[t] = sscale[c_seg_id[t]];
}

// ---------------- pass 3: out = x * scale[ch] ----------------
__global__ __launch_bounds__(NTHREADS) void k_scale(
        const float4* __restrict__ x4, const float* __restrict__ chscale,
        float4* __restrict__ o4) {
    const int slab = blockIdx.x / BPS;
    const int sub  = blockIdx.x % BPS;
    const int ch   = slab & (NCH - 1);
    const float s  = chscale[ch];        // block-uniform -> scalar load
    const long base = (long)slab * SLAB4 + (long)sub * CHUNK4 + threadIdx.x;

    #pragma unroll
    for (int k = 0; k < ITERS; ++k) {
        const long i = base + (long)k * NTHREADS;
        float4 v = x4[i];
        v.x *= s; v.y *= s; v.z *= s; v.w *= s;
        o4[i] = v;
    }
}

extern "C" void kernel_launch(void* const* d_in, const int* in_sizes, int n_in,
                              void* d_out, int out_size, void* d_ws, size_t ws_size,
                              hipStream_t stream) {
    const float4* x4     = (const float4*)d_in[0];
    const float*  sigma2 = (const float*)d_in[1];
    const int*    update = (const int*)d_in[2];
    float*        out4   = (float*)d_out;

    float* partial = (float*)d_ws;            // [2048], overwritten every call
    float* chscale = partial + NPART;         // [64],   overwritten every call

    k_reduce_abs<<<NPART, NTHREADS, 0, stream>>>(x4, partial);
    k_stats<<<1, 64, 0, stream>>>(partial, sigma2, update, chscale);
    k_scale<<<NSLAB * BPS, NTHREADS, 0, stream>>>(x4, chscale, (float4*)out4);
}

// Round 4
// 122.847 us; speedup vs baseline: 1.3003x; 1.3003x over previous
//
#include <hip/hip_runtime.h>
#include <math.h>

// Problem geometry (from reference): x [8, 64, 256, 256, 2] fp32
// slab = one (b, ch) contiguous run = 256*256*2 = 131072 floats = 32768 float4
#define NCH      64
#define NB       8
#define NSLAB    512                 // 8 * 64
#define SLAB4    32768               // float4 per slab
#define BPS      4                   // blocks per slab
#define CHUNK4   (SLAB4 / BPS)       // 8192 float4 per block
#define NTHREADS 256
#define ITERS    (CHUNK4 / NTHREADS) // 32
#define NSEG     16
#define NPART    (NSLAB * BPS)       // 2048 partial sums
#define PER_CH_ELEMS 1048576.0f      // 8*256*256*2 elements per channel

typedef float f4 __attribute__((ext_vector_type(4)));   // clang vector: NT-store OK

__device__ __constant__ int c_seg_id[NCH] = {
    0,1,2,3,
    4,4,4, 5,5,5, 6,6,6, 7,7,7,
    8,8,8,8,8, 9,9,9,9,9, 10,10,10,10,10, 11,11,11,11,11,
    12,12,12,12,12,12,12, 13,13,13,13,13,13,13,
    14,14,14,14,14,14,14, 15,15,15,15,15,15,15
};
__device__ __constant__ int c_seg_lo[NSEG]  = {0,1,2,3, 4,7,10,13, 16,21,26,31, 36,43,50,57};
__device__ __constant__ int c_seg_sz[NSEG]  = {1,1,1,1, 3,3,3,3,   5,5,5,5,     7,7,7,7};

// ---------------- pass 1: per-block partial sums of |x| (plain stores, no atomics) ----
__global__ __launch_bounds__(NTHREADS) void k_reduce_abs(
        const f4* __restrict__ x4, float* __restrict__ partial) {
    const long base = (long)blockIdx.x * CHUNK4 + threadIdx.x;

    float s = 0.0f;
    #pragma unroll
    for (int k = 0; k < ITERS; ++k) {
        f4 v = x4[base + (long)k * NTHREADS];
        s += fabsf(v.x) + fabsf(v.y) + fabsf(v.z) + fabsf(v.w);
    }
    // 64-lane wave reduction
    #pragma unroll
    for (int off = 32; off >= 1; off >>= 1) s += __shfl_down(s, off, 64);

    __shared__ float sm[NTHREADS / 64];
    const int lane = threadIdx.x & 63;
    const int wid  = threadIdx.x >> 6;
    if (lane == 0) sm[wid] = s;
    __syncthreads();
    if (threadIdx.x == 0)
        partial[blockIdx.x] = sm[0] + sm[1] + sm[2] + sm[3];   // overwrite, never accumulate
}

// ---------------- pass 2 (fused into pass 3): out = x * scale[ch] ----------------
// Each block recomputes its channel's scale from the 2048 partials (L2-cached,
// identical FP sequence in every block of the same segment -> deterministic).
// Stores are non-temporal so the 256 MiB output stream does not evict x from
// the 256 MiB Infinity Cache; pass-3 reads then hit L3 (x was just streamed
// through it by pass 1 in the same address order).
__global__ __launch_bounds__(NTHREADS) void k_scale(
        const f4* __restrict__ x4, const float* __restrict__ partial,
        const float* __restrict__ sigma2, const int* __restrict__ update,
        f4* __restrict__ o4) {
    const int slab = blockIdx.x / BPS;
    const int sub  = blockIdx.x % BPS;
    const int ch   = slab & (NCH - 1);

    // --- derive scale for this block's channel ---
    const int seg = c_seg_id[ch];
    const int lo  = c_seg_lo[seg];
    const int n   = c_seg_sz[seg];     // 1..7 -> n*32 partials, <= 224
    const int tid = threadIdx.x;

    float v = 0.0f;
    if (tid < n * 32) {
        const int c  = lo + (tid >> 5);
        const int r  = tid & 31;
        const int b  = r >> 2;
        const int sb = r & 3;
        v = partial[(b * NCH + c) * BPS + sb];
    }
    #pragma unroll
    for (int off = 32; off >= 1; off >>= 1) v += __shfl_down(v, off, 64);

    __shared__ float sm[NTHREADS / 64];
    __shared__ float s_scale;
    const int lane = tid & 63;
    const int wid  = tid >> 6;
    if (lane == 0) sm[wid] = v;
    __syncthreads();
    if (tid == 0) {
        const float segsum = sm[0] + sm[1] + sm[2] + sm[3];
        const float s2  = segsum / ((float)n * PER_CH_ELEMS);
        const float old = sigma2[seg];
        float snew;
        if (update[0] != 0) snew = (old == 0.0f) ? s2 : old * 0.9f + s2 * 0.1f;
        else                snew = old;
        s_scale = 1.0f / (sqrtf(snew) + 1e-5f);
    }
    __syncthreads();
    const float s = s_scale;

    // --- streaming scale: L3-fed reads, NT writes ---
    const long base = (long)slab * SLAB4 + (long)sub * CHUNK4 + tid;
    #pragma unroll
    for (int k = 0; k < ITERS; ++k) {
        const long i = base + (long)k * NTHREADS;
        f4 t = x4[i];
        t *= s;
        __builtin_nontemporal_store(t, &o4[i]);
    }
}

extern "C" void kernel_launch(void* const* d_in, const int* in_sizes, int n_in,
                              void* d_out, int out_size, void* d_ws, size_t ws_size,
                              hipStream_t stream) {
    const f4*     x4     = (const f4*)d_in[0];
    const float*  sigma2 = (const float*)d_in[1];
    const int*    update = (const int*)d_in[2];

    float* partial = (float*)d_ws;            // [2048], overwritten every call

    k_reduce_abs<<<NPART, NTHREADS, 0, stream>>>(x4, partial);
    k_scale<<<NSLAB * BPS, NTHREADS, 0, stream>>>(x4, partial, sigma2, update,
                                                  (f4*)d_out);
}

// Round 5
// 122.754 us; speedup vs baseline: 1.3013x; 1.0008x over previous
//
#include <hip/hip_runtime.h>
#include <math.h>

// Problem geometry (from reference): x [8, 64, 256, 256, 2] fp32
// slab = one (b, ch) contiguous run = 256*256*2 = 131072 floats = 32768 float4
#define NCH      64
#define NB       8
#define NSLAB    512                 // 8 * 64
#define SLAB4    32768               // float4 per slab
#define BPS      4                   // blocks per slab
#define CHUNK4   (SLAB4 / BPS)       // 8192 float4 per block
#define NTHREADS 256
#define ITERS    (CHUNK4 / NTHREADS) // 32
#define NSEG     16
#define NPART    (NSLAB * BPS)       // 2048 partial sums
#define PER_CH_ELEMS 1048576.0f      // 8*256*256*2 elements per channel

typedef float f4 __attribute__((ext_vector_type(4)));   // clang vector: NT-store OK

__device__ __constant__ int c_seg_id[NCH] = {
    0,1,2,3,
    4,4,4, 5,5,5, 6,6,6, 7,7,7,
    8,8,8,8,8, 9,9,9,9,9, 10,10,10,10,10, 11,11,11,11,11,
    12,12,12,12,12,12,12, 13,13,13,13,13,13,13,
    14,14,14,14,14,14,14, 15,15,15,15,15,15,15
};
__device__ __constant__ int c_seg_lo[NSEG]  = {0,1,2,3, 4,7,10,13, 16,21,26,31, 36,43,50,57};
__device__ __constant__ int c_seg_sz[NSEG]  = {1,1,1,1, 3,3,3,3,   5,5,5,5,     7,7,7,7};

// ---------------- pass 1: per-block partial sums of |x| (plain stores, no atomics) ----
__global__ __launch_bounds__(NTHREADS) void k_reduce_abs(
        const f4* __restrict__ x4, float* __restrict__ partial) {
    const long base = (long)blockIdx.x * CHUNK4 + threadIdx.x;

    float s = 0.0f;
    #pragma unroll
    for (int k = 0; k < ITERS; ++k) {
        f4 v = x4[base + (long)k * NTHREADS];
        s += fabsf(v.x) + fabsf(v.y) + fabsf(v.z) + fabsf(v.w);
    }
    // 64-lane wave reduction
    #pragma unroll
    for (int off = 32; off >= 1; off >>= 1) s += __shfl_down(s, off, 64);

    __shared__ float sm[NTHREADS / 64];
    const int lane = threadIdx.x & 63;
    const int wid  = threadIdx.x >> 6;
    if (lane == 0) sm[wid] = s;
    __syncthreads();
    if (threadIdx.x == 0)
        partial[blockIdx.x] = sm[0] + sm[1] + sm[2] + sm[3];   // overwrite, never accumulate
}

// ---------------- pass 2 (fused into pass 3): out = x * scale[ch] ----------------
// Each block recomputes its channel's scale from the 2048 partials (L2-cached,
// identical FP sequence in every block of the same segment -> deterministic).
// NT stores: the 256 MiB output stream must not evict x from the 256 MiB MALL.
// REVERSE traversal: pass1 streamed x forward, so the tail of x is MRU in L3.
// Walking pass3 backwards (block-chunk and 4KiB-step granularity; lanes stay
// ascending for coalescing) consumes lines before their LRU eviction turn.
__global__ __launch_bounds__(NTHREADS) void k_scale(
        const f4* __restrict__ x4, const float* __restrict__ partial,
        const float* __restrict__ sigma2, const int* __restrict__ update,
        f4* __restrict__ o4) {
    const int rb   = (NSLAB * BPS - 1) - blockIdx.x;   // reversed chunk index
    const int slab = rb / BPS;
    const int sub  = rb % BPS;
    const int ch   = slab & (NCH - 1);

    // --- derive scale for this block's channel ---
    const int seg = c_seg_id[ch];
    const int lo  = c_seg_lo[seg];
    const int n   = c_seg_sz[seg];     // 1..7 -> n*32 partials, <= 224
    const int tid = threadIdx.x;

    float v = 0.0f;
    if (tid < n * 32) {
        const int c  = lo + (tid >> 5);
        const int r  = tid & 31;
        const int b  = r >> 2;
        const int sb = r & 3;
        v = partial[(b * NCH + c) * BPS + sb];
    }
    #pragma unroll
    for (int off = 32; off >= 1; off >>= 1) v += __shfl_down(v, off, 64);

    __shared__ float sm[NTHREADS / 64];
    __shared__ float s_scale;
    const int lane = tid & 63;
    const int wid  = tid >> 6;
    if (lane == 0) sm[wid] = v;
    __syncthreads();
    if (tid == 0) {
        const float segsum = sm[0] + sm[1] + sm[2] + sm[3];
        const float s2  = segsum / ((float)n * PER_CH_ELEMS);
        const float old = sigma2[seg];
        float snew;
        if (update[0] != 0) snew = (old == 0.0f) ? s2 : old * 0.9f + s2 * 0.1f;
        else                snew = old;
        s_scale = 1.0f / (sqrtf(snew) + 1e-5f);
    }
    __syncthreads();
    const float s = s_scale;

    // --- streaming scale, walked backwards: L3-MRU-fed reads, NT writes ---
    const long base = (long)slab * SLAB4 + (long)sub * CHUNK4 + tid;
    #pragma unroll
    for (int k = ITERS - 1; k >= 0; --k) {
        const long i = base + (long)k * NTHREADS;
        f4 t = x4[i];
        t *= s;
        __builtin_nontemporal_store(t, &o4[i]);
    }
}

extern "C" void kernel_launch(void* const* d_in, const int* in_sizes, int n_in,
                              void* d_out, int out_size, void* d_ws, size_t ws_size,
                              hipStream_t stream) {
    const f4*     x4     = (const f4*)d_in[0];
    const float*  sigma2 = (const float*)d_in[1];
    const int*    update = (const int*)d_in[2];

    float* partial = (float*)d_ws;            // [2048], overwritten every call

    k_reduce_abs<<<NPART, NTHREADS, 0, stream>>>(x4, partial);
    k_scale<<<NSLAB * BPS, NTHREADS, 0, stream>>>(x4, partial, sigma2, update,
                                                  (f4*)d_out);
}